// Round 1
// baseline (1383.407 us; speedup 1.0000x reference)
//
#include <hip/hip_runtime.h>
#include <float.h>
#include <limits.h>

#define NB     16
#define QLEN   32
#define HDIM   128
#define NPIDS  500
#define NDOCS  10000
#define DLEN   200
#define TOPK   100

// ---------------- Kernel 1: per-row sort + dedupe (dup -> -1) ----------------
__global__ __launch_bounds__(512) void dedupe_kernel(const int* __restrict__ pids,
                                                     const int* __restrict__ boundaries,
                                                     int* __restrict__ dpids) {
    __shared__ int s[512];
    const int b = blockIdx.x;
    const int t = threadIdx.x;
    const int lo = boundaries[0];

    int v = INT_MAX;   // padding sentinel, sorts to the end
    if (t < NPIDS) {
        int p = pids[b * NPIDS + t] - lo;
        if (p < 0 || p >= NDOCS) p = -1;
        v = p;
    }
    s[t] = v;
    __syncthreads();

    // bitonic sort ascending over 512 elements
    for (int k = 2; k <= 512; k <<= 1) {
        for (int j = k >> 1; j > 0; j >>= 1) {
            int ixj = t ^ j;
            if (ixj > t) {
                int a = s[t], c = s[ixj];
                bool up = ((t & k) == 0);
                if ((a > c) == up) { s[t] = c; s[ixj] = a; }
            }
            __syncthreads();
        }
    }

    if (t < NPIDS) {
        int val = s[t];
        int o = val;
        if (val == INT_MAX) o = -1;                    // guard (shouldn't occur)
        else if (t > 0 && val == s[t - 1]) o = -1;     // duplicate -> -1
        dpids[b * NPIDS + t] = o;
    }
}

// ---------------- Kernel 2: MaxSim score per candidate ----------------
// One block (256 threads) per (batch, candidate).
// thread t: q-row qi = t>>3 (0..31), h-slice hs = t&7 (16 floats each).
__global__ __launch_bounds__(256) void score_kernel(const float* __restrict__ qv,
                                                    const float* __restrict__ vectors,
                                                    const int* __restrict__ dpids,
                                                    float* __restrict__ scores) {
    const int blk = blockIdx.x;
    const int b = blk / NPIDS;
    const int kk = blk - b * NPIDS;
    const int t = threadIdx.x;
    const int qi = t >> 3;
    const int hs = t & 7;

    const int pid = dpids[b * NPIDS + kk];
    if (pid < 0) {
        if (t == 0) scores[b * NPIDS + kk] = -__builtin_inff();
        return;
    }

    // q fragment: q[b][qi][hs*16 .. hs*16+15]
    const float4* qp = (const float4*)(qv + ((size_t)b * QLEN + qi) * HDIM) + hs * 4;
    const float4 q0 = qp[0], q1 = qp[1], q2 = qp[2], q3 = qp[3];

    const float4* __restrict__ vbase =
        (const float4*)(vectors + (size_t)pid * (DLEN * HDIM)) + hs * 4;

    float mx = -FLT_MAX;
    #pragma unroll 4
    for (int d = 0; d < DLEN; ++d) {
        const float4* row = vbase + d * (HDIM / 4);
        float4 v0 = row[0], v1 = row[1], v2 = row[2], v3 = row[3];

        float s0 = q0.x * v0.x + q0.y * v0.y + q0.z * v0.z + q0.w * v0.w;
        float s1 = q1.x * v1.x + q1.y * v1.y + q1.z * v1.z + q1.w * v1.w;
        float s2 = q2.x * v2.x + q2.y * v2.y + q2.z * v2.z + q2.w * v2.w;
        float s3 = q3.x * v3.x + q3.y * v3.y + q3.z * v3.z + q3.w * v3.w;
        float s = (s0 + s1) + (s2 + s3);

        // reduce across the 8 h-slices (lanes differing in bits 0..2)
        s += __shfl_xor(s, 1);
        s += __shfl_xor(s, 2);
        s += __shfl_xor(s, 4);

        mx = fmaxf(mx, s);
    }

    __shared__ float smax[QLEN];
    if (hs == 0) smax[qi] = mx;
    __syncthreads();

    if (t == 0) {
        double acc = 0.0;
        #pragma unroll
        for (int i = 0; i < QLEN; ++i) acc += (double)smax[i];
        scores[b * NPIDS + kk] = (float)acc;
    }
}

// ---------------- Kernel 3: per-batch top-100 (sorted desc) ----------------
__global__ __launch_bounds__(512) void topk_kernel(const float* __restrict__ scores,
                                                   const int* __restrict__ dpids,
                                                   const int* __restrict__ boundaries,
                                                   float* __restrict__ out) {
    __shared__ float ss[512];
    __shared__ int   sp[512];
    const int b = blockIdx.x;
    const int t = threadIdx.x;
    const int lo = boundaries[0];

    float sc = -__builtin_inff();
    int   p  = -1;
    if (t < NPIDS) {
        p = dpids[b * NPIDS + t];
        sc = (p < 0) ? -__builtin_inff() : scores[b * NPIDS + t];
    }
    ss[t] = sc;
    sp[t] = p;
    __syncthreads();

    // bitonic sort DESCENDING by score, pid carried
    for (int k = 2; k <= 512; k <<= 1) {
        for (int j = k >> 1; j > 0; j >>= 1) {
            int ixj = t ^ j;
            if (ixj > t) {
                float a = ss[t], c = ss[ixj];
                bool down = ((t & k) == 0);   // descending region
                bool swap = down ? (a < c) : (a > c);
                if (swap) {
                    int pa = sp[t], pc = sp[ixj];
                    ss[t] = c;   ss[ixj] = a;
                    sp[t] = pc;  sp[ixj] = pa;
                }
            }
            __syncthreads();
        }
    }

    if (t < TOPK) {
        out[b * TOPK + t] = ss[t];
        int pp = sp[t];
        out[NB * TOPK + b * TOPK + t] = (pp >= 0) ? (float)(pp + lo) : -1.0f;
    }
}

// ---------------- launch ----------------
extern "C" void kernel_launch(void* const* d_in, const int* in_sizes, int n_in,
                              void* d_out, int out_size, void* d_ws, size_t ws_size,
                              hipStream_t stream) {
    const float* qv        = (const float*)d_in[0];
    const int*   pids      = (const int*)d_in[1];
    const float* vectors   = (const float*)d_in[2];
    const int*   boundaries= (const int*)d_in[3];

    int*   dpids  = (int*)d_ws;
    float* scores = (float*)((char*)d_ws + ((NB * NPIDS * sizeof(int) + 255) & ~255));

    dedupe_kernel<<<NB, 512, 0, stream>>>(pids, boundaries, dpids);
    score_kernel<<<NB * NPIDS, 256, 0, stream>>>(qv, vectors, dpids, scores);
    topk_kernel<<<NB, 512, 0, stream>>>(scores, dpids, boundaries, (float*)d_out);
}

// Round 2
// 512.584 us; speedup vs baseline: 2.6989x; 2.6989x over previous
//
#include <hip/hip_runtime.h>
#include <float.h>
#include <limits.h>

#define NB     16
#define QLEN   32
#define HDIM   128
#define NPIDS  500
#define NDOCS  10000
#define DLEN   200
#define TOPK   100

// ---------------- Kernel 1: per-row sort + dedupe (dup -> -1) ----------------
__global__ __launch_bounds__(512) void dedupe_kernel(const int* __restrict__ pids,
                                                     const int* __restrict__ boundaries,
                                                     int* __restrict__ dpids) {
    __shared__ int s[512];
    const int b = blockIdx.x;
    const int t = threadIdx.x;
    const int lo = boundaries[0];

    int v = INT_MAX;   // padding sentinel, sorts to the end
    if (t < NPIDS) {
        int p = pids[b * NPIDS + t] - lo;
        if (p < 0 || p >= NDOCS) p = -1;
        v = p;
    }
    s[t] = v;
    __syncthreads();

    // bitonic sort ascending over 512 elements
    for (int k = 2; k <= 512; k <<= 1) {
        for (int j = k >> 1; j > 0; j >>= 1) {
            int ixj = t ^ j;
            if (ixj > t) {
                int a = s[t], c = s[ixj];
                bool up = ((t & k) == 0);
                if ((a > c) == up) { s[t] = c; s[ixj] = a; }
            }
            __syncthreads();
        }
    }

    if (t < NPIDS) {
        int val = s[t];
        int o = val;
        if (val == INT_MAX) o = -1;                    // guard (shouldn't occur)
        else if (t > 0 && val == s[t - 1]) o = -1;     // duplicate -> -1
        dpids[b * NPIDS + t] = o;
    }
}

// ---------------- Kernel 2: MaxSim score per candidate ----------------
// One block (256 threads = 4 waves) per (batch, candidate).
// lane = (qg<<3)|ksl: thread holds q-rows [4qg..4qg+3] x k-slice [16ksl..16ksl+15]
// in registers. Waves partition the 200 doc tokens (50 each). Per token:
// 4 float4 global loads -> 64 FMAs -> 3-round butterfly over the 8 ksl lanes
// per accumulator -> running max per q-row.
__global__ __launch_bounds__(256) void score_kernel(const float* __restrict__ qv,
                                                    const float* __restrict__ vectors,
                                                    const int* __restrict__ dpids,
                                                    float* __restrict__ scores) {
    const int blk = blockIdx.x;
    const int b  = blk / NPIDS;
    const int kk = blk - b * NPIDS;
    const int t    = threadIdx.x;
    const int w    = t >> 6;        // wave id 0..3
    const int lane = t & 63;
    const int qg   = lane >> 3;     // 0..7 -> q rows 4qg..4qg+3
    const int ksl  = lane & 7;      // 0..7 -> k slice of 16

    const int pid = dpids[b * NPIDS + kk];
    if (pid < 0) {
        if (t == 0) scores[b * NPIDS + kk] = -__builtin_inff();
        return;
    }

    // Q fragments: 4 rows x 16 floats, held in registers for the whole kernel
    const float* qb = qv + ((size_t)b * QLEN) * HDIM + ksl * 16;
    float4 q[4][4];
    #pragma unroll
    for (int r = 0; r < 4; ++r) {
        const float4* qr = (const float4*)(qb + (size_t)(4 * qg + r) * HDIM);
        #pragma unroll
        for (int c = 0; c < 4; ++c) q[r][c] = qr[c];
    }

    const float* vb = vectors + (size_t)pid * (DLEN * HDIM) + ksl * 16;

    float rmax[4] = { -FLT_MAX, -FLT_MAX, -FLT_MAX, -FLT_MAX };

    const int d0 = w * (DLEN / 4);           // 50 tokens per wave
    #pragma unroll 2
    for (int d = d0; d < d0 + (DLEN / 4); ++d) {
        const float4* vr = (const float4*)(vb + (size_t)d * HDIM);
        const float4 v0 = vr[0], v1 = vr[1], v2 = vr[2], v3 = vr[3];

        float acc[4];
        #pragma unroll
        for (int r = 0; r < 4; ++r) {
            float s0 = q[r][0].x * v0.x + q[r][0].y * v0.y + q[r][0].z * v0.z + q[r][0].w * v0.w;
            float s1 = q[r][1].x * v1.x + q[r][1].y * v1.y + q[r][1].z * v1.z + q[r][1].w * v1.w;
            float s2 = q[r][2].x * v2.x + q[r][2].y * v2.y + q[r][2].z * v2.z + q[r][2].w * v2.w;
            float s3 = q[r][3].x * v3.x + q[r][3].y * v3.y + q[r][3].z * v3.z + q[r][3].w * v3.w;
            acc[r] = (s0 + s1) + (s2 + s3);
        }

        // butterfly sum over the 8 ksl lanes (masks 1,2,4 stay inside the group)
        #pragma unroll
        for (int r = 0; r < 4; ++r) {
            float a = acc[r];
            a += __shfl_xor(a, 1);
            a += __shfl_xor(a, 2);
            a += __shfl_xor(a, 4);
            rmax[r] = fmaxf(rmax[r], a);
        }
    }

    // combine partial maxes across the 4 waves
    __shared__ float smax[4][QLEN];
    if (ksl == 0) {
        #pragma unroll
        for (int r = 0; r < 4; ++r) smax[w][4 * qg + r] = rmax[r];
    }
    __syncthreads();

    if (w == 0) {
        const int qi = lane & 31;            // lanes 32..63 duplicate 0..31
        float m = smax[0][qi];
        m = fmaxf(m, smax[1][qi]);
        m = fmaxf(m, smax[2][qi]);
        m = fmaxf(m, smax[3][qi]);
        double ds = (double)m;
        ds += __shfl_xor(ds, 1);
        ds += __shfl_xor(ds, 2);
        ds += __shfl_xor(ds, 4);
        ds += __shfl_xor(ds, 8);
        ds += __shfl_xor(ds, 16);
        if (t == 0) scores[b * NPIDS + kk] = (float)ds;
    }
}

// ---------------- Kernel 3: per-batch top-100 (sorted desc) ----------------
__global__ __launch_bounds__(512) void topk_kernel(const float* __restrict__ scores,
                                                   const int* __restrict__ dpids,
                                                   const int* __restrict__ boundaries,
                                                   float* __restrict__ out) {
    __shared__ float ss[512];
    __shared__ int   sp[512];
    const int b = blockIdx.x;
    const int t = threadIdx.x;
    const int lo = boundaries[0];

    float sc = -__builtin_inff();
    int   p  = -1;
    if (t < NPIDS) {
        p = dpids[b * NPIDS + t];
        sc = (p < 0) ? -__builtin_inff() : scores[b * NPIDS + t];
    }
    ss[t] = sc;
    sp[t] = p;
    __syncthreads();

    // bitonic sort DESCENDING by score, pid carried
    for (int k = 2; k <= 512; k <<= 1) {
        for (int j = k >> 1; j > 0; j >>= 1) {
            int ixj = t ^ j;
            if (ixj > t) {
                float a = ss[t], c = ss[ixj];
                bool down = ((t & k) == 0);   // descending region
                bool swap = down ? (a < c) : (a > c);
                if (swap) {
                    int pa = sp[t], pc = sp[ixj];
                    ss[t] = c;   ss[ixj] = a;
                    sp[t] = pc;  sp[ixj] = pa;
                }
            }
            __syncthreads();
        }
    }

    if (t < TOPK) {
        out[b * TOPK + t] = ss[t];
        int pp = sp[t];
        out[NB * TOPK + b * TOPK + t] = (pp >= 0) ? (float)(pp + lo) : -1.0f;
    }
}

// ---------------- launch ----------------
extern "C" void kernel_launch(void* const* d_in, const int* in_sizes, int n_in,
                              void* d_out, int out_size, void* d_ws, size_t ws_size,
                              hipStream_t stream) {
    const float* qv        = (const float*)d_in[0];
    const int*   pids      = (const int*)d_in[1];
    const float* vectors   = (const float*)d_in[2];
    const int*   boundaries= (const int*)d_in[3];

    int*   dpids  = (int*)d_ws;
    float* scores = (float*)((char*)d_ws + ((NB * NPIDS * sizeof(int) + 255) & ~255));

    dedupe_kernel<<<NB, 512, 0, stream>>>(pids, boundaries, dpids);
    score_kernel<<<NB * NPIDS, 256, 0, stream>>>(qv, vectors, dpids, scores);
    topk_kernel<<<NB, 512, 0, stream>>>(scores, dpids, boundaries, (float*)d_out);
}

// Round 3
// 485.383 us; speedup vs baseline: 2.8501x; 1.0560x over previous
//
#include <hip/hip_runtime.h>
#include <float.h>
#include <limits.h>

#define NB     16
#define QLEN   32
#define HDIM   128
#define NPIDS  500
#define NDOCS  10000
#define DLEN   200
#define TOPK   100

// ---------------- Kernel 1: per-row sort + dedupe (dup -> -1) ----------------
__global__ __launch_bounds__(512) void dedupe_kernel(const int* __restrict__ pids,
                                                     const int* __restrict__ boundaries,
                                                     int* __restrict__ dpids) {
    __shared__ int s[512];
    const int b = blockIdx.x;
    const int t = threadIdx.x;
    const int lo = boundaries[0];

    int v = INT_MAX;   // padding sentinel, sorts to the end
    if (t < NPIDS) {
        int p = pids[b * NPIDS + t] - lo;
        if (p < 0 || p >= NDOCS) p = -1;
        v = p;
    }
    s[t] = v;
    __syncthreads();

    // bitonic sort ascending over 512 elements
    for (int k = 2; k <= 512; k <<= 1) {
        for (int j = k >> 1; j > 0; j >>= 1) {
            int ixj = t ^ j;
            if (ixj > t) {
                int a = s[t], c = s[ixj];
                bool up = ((t & k) == 0);
                if ((a > c) == up) { s[t] = c; s[ixj] = a; }
            }
            __syncthreads();
        }
    }

    if (t < NPIDS) {
        int val = s[t];
        int o = val;
        if (val == INT_MAX) o = -1;                    // guard (shouldn't occur)
        else if (t > 0 && val == s[t - 1]) o = -1;     // duplicate -> -1
        dpids[b * NPIDS + t] = o;
    }
}

// ---------------- Kernel 2: MaxSim score per candidate ----------------
// One block (256 threads = 4 waves) per (batch, candidate).
// Thread t owns doc token d (t>=200 duplicates d=t-56: max-invariant padding).
// Outer-product accumulate: acc[qi] += q[qi][k] * v[d][k] over k, all in
// registers; q addresses are wave-uniform (broadcast, L1/L2-hot 16KB).
// ZERO cross-lane ops in the main loop; one butterfly reduction at the end.
__global__ __launch_bounds__(256) void score_kernel(const float* __restrict__ qv,
                                                    const float* __restrict__ vectors,
                                                    const int* __restrict__ dpids,
                                                    float* __restrict__ scores) {
    const int blk = blockIdx.x;
    const int b  = blk / NPIDS;
    const int kk = blk - b * NPIDS;
    const int t    = threadIdx.x;
    const int w    = t >> 6;        // wave id 0..3
    const int lane = t & 63;

    const int pid = dpids[b * NPIDS + kk];
    if (pid < 0) {
        if (t == 0) scores[b * NPIDS + kk] = -__builtin_inff();
        return;
    }

    const int d = (t < DLEN) ? t : t - 56;   // 200..255 -> 144..199 (dup, harmless)
    const float* __restrict__ vrow = vectors + ((size_t)pid * DLEN + d) * HDIM;
    const float* __restrict__ Qb   = qv + (size_t)b * QLEN * HDIM;

    float acc[QLEN];
    #pragma unroll
    for (int qi = 0; qi < QLEN; ++qi) acc[qi] = 0.0f;

    // prime chunk 0 (16 floats = one 64B line per lane)
    float4 v0, v1, v2, v3;
    {
        const float4* vp = (const float4*)vrow;
        v0 = vp[0]; v1 = vp[1]; v2 = vp[2]; v3 = vp[3];
    }

    #pragma unroll
    for (int c = 0; c < HDIM / 16; ++c) {
        // prefetch next chunk (c==7 wraps to 0: redundant, harmless)
        float4 n0, n1, n2, n3;
        {
            const int cn = (c + 1) & 7;
            const float4* vp = (const float4*)(vrow + cn * 16);
            n0 = vp[0]; n1 = vp[1]; n2 = vp[2]; n3 = vp[3];
        }

        const float* qk = Qb + c * 16;
        #pragma unroll
        for (int qi = 0; qi < QLEN; ++qi) {
            const float4* qp = (const float4*)(qk + (size_t)qi * HDIM);
            const float4 a = qp[0], e = qp[1], f = qp[2], g = qp[3];
            float s = acc[qi];
            s = fmaf(a.x, v0.x, s); s = fmaf(a.y, v0.y, s);
            s = fmaf(a.z, v0.z, s); s = fmaf(a.w, v0.w, s);
            s = fmaf(e.x, v1.x, s); s = fmaf(e.y, v1.y, s);
            s = fmaf(e.z, v1.z, s); s = fmaf(e.w, v1.w, s);
            s = fmaf(f.x, v2.x, s); s = fmaf(f.y, v2.y, s);
            s = fmaf(f.z, v2.z, s); s = fmaf(f.w, v2.w, s);
            s = fmaf(g.x, v3.x, s); s = fmaf(g.y, v3.y, s);
            s = fmaf(g.z, v3.z, s); s = fmaf(g.w, v3.w, s);
            acc[qi] = s;
        }

        v0 = n0; v1 = n1; v2 = n2; v3 = n3;
    }

    // per-wave max over the 64 lanes (d-space) for each qi
    __shared__ float wmax[4][QLEN];
    #pragma unroll
    for (int qi = 0; qi < QLEN; ++qi) {
        float m = acc[qi];
        m = fmaxf(m, __shfl_xor(m, 1));
        m = fmaxf(m, __shfl_xor(m, 2));
        m = fmaxf(m, __shfl_xor(m, 4));
        m = fmaxf(m, __shfl_xor(m, 8));
        m = fmaxf(m, __shfl_xor(m, 16));
        m = fmaxf(m, __shfl_xor(m, 32));
        if (lane == 0) wmax[w][qi] = m;
    }
    __syncthreads();

    // wave 0: combine 4 wave-maxes, then sum the 32 q-maxes (double)
    if (w == 0) {
        double ds = 0.0;
        if (lane < QLEN) {
            float m = wmax[0][lane];
            m = fmaxf(m, wmax[1][lane]);
            m = fmaxf(m, wmax[2][lane]);
            m = fmaxf(m, wmax[3][lane]);
            ds = (double)m;
        }
        ds += __shfl_xor(ds, 1);
        ds += __shfl_xor(ds, 2);
        ds += __shfl_xor(ds, 4);
        ds += __shfl_xor(ds, 8);
        ds += __shfl_xor(ds, 16);
        ds += __shfl_xor(ds, 32);
        if (t == 0) scores[b * NPIDS + kk] = (float)ds;
    }
}

// ---------------- Kernel 3: per-batch top-100 (sorted desc) ----------------
__global__ __launch_bounds__(512) void topk_kernel(const float* __restrict__ scores,
                                                   const int* __restrict__ dpids,
                                                   const int* __restrict__ boundaries,
                                                   float* __restrict__ out) {
    __shared__ float ss[512];
    __shared__ int   sp[512];
    const int b = blockIdx.x;
    const int t = threadIdx.x;
    const int lo = boundaries[0];

    float sc = -__builtin_inff();
    int   p  = -1;
    if (t < NPIDS) {
        p = dpids[b * NPIDS + t];
        sc = (p < 0) ? -__builtin_inff() : scores[b * NPIDS + t];
    }
    ss[t] = sc;
    sp[t] = p;
    __syncthreads();

    // bitonic sort DESCENDING by score, pid carried
    for (int k = 2; k <= 512; k <<= 1) {
        for (int j = k >> 1; j > 0; j >>= 1) {
            int ixj = t ^ j;
            if (ixj > t) {
                float a = ss[t], c = ss[ixj];
                bool down = ((t & k) == 0);   // descending region
                bool swap = down ? (a < c) : (a > c);
                if (swap) {
                    int pa = sp[t], pc = sp[ixj];
                    ss[t] = c;   ss[ixj] = a;
                    sp[t] = pc;  sp[ixj] = pa;
                }
            }
            __syncthreads();
        }
    }

    if (t < TOPK) {
        out[b * TOPK + t] = ss[t];
        int pp = sp[t];
        out[NB * TOPK + b * TOPK + t] = (pp >= 0) ? (float)(pp + lo) : -1.0f;
    }
}

// ---------------- launch ----------------
extern "C" void kernel_launch(void* const* d_in, const int* in_sizes, int n_in,
                              void* d_out, int out_size, void* d_ws, size_t ws_size,
                              hipStream_t stream) {
    const float* qv        = (const float*)d_in[0];
    const int*   pids      = (const int*)d_in[1];
    const float* vectors   = (const float*)d_in[2];
    const int*   boundaries= (const int*)d_in[3];

    int*   dpids  = (int*)d_ws;
    float* scores = (float*)((char*)d_ws + ((NB * NPIDS * sizeof(int) + 255) & ~255));

    dedupe_kernel<<<NB, 512, 0, stream>>>(pids, boundaries, dpids);
    score_kernel<<<NB * NPIDS, 256, 0, stream>>>(qv, vectors, dpids, scores);
    topk_kernel<<<NB, 512, 0, stream>>>(scores, dpids, boundaries, (float*)d_out);
}

// Round 4
// 237.925 us; speedup vs baseline: 5.8145x; 2.0401x over previous
//
#include <hip/hip_runtime.h>
#include <float.h>
#include <limits.h>

#define NB     16
#define QLEN   32
#define HDIM   128
#define NPIDS  500
#define NDOCS  10000
#define DLEN   200
#define TOPK   100
#define VROW   (DLEN * HDIM)

typedef __bf16 bf16x8 __attribute__((ext_vector_type(8)));
typedef float  f32x16 __attribute__((ext_vector_type(16)));

// ---------------- Kernel 1: per-row sort + dedupe (dup -> -1) ----------------
__global__ __launch_bounds__(512) void dedupe_kernel(const int* __restrict__ pids,
                                                     const int* __restrict__ boundaries,
                                                     int* __restrict__ dpids) {
    __shared__ int s[512];
    const int b = blockIdx.x;
    const int t = threadIdx.x;
    const int lo = boundaries[0];

    int v = INT_MAX;
    if (t < NPIDS) {
        int p = pids[b * NPIDS + t] - lo;
        if (p < 0 || p >= NDOCS) p = -1;
        v = p;
    }
    s[t] = v;
    __syncthreads();

    for (int k = 2; k <= 512; k <<= 1) {
        for (int j = k >> 1; j > 0; j >>= 1) {
            int ixj = t ^ j;
            if (ixj > t) {
                int a = s[t], c = s[ixj];
                bool up = ((t & k) == 0);
                if ((a > c) == up) { s[t] = c; s[ixj] = a; }
            }
            __syncthreads();
        }
    }

    if (t < NPIDS) {
        int val = s[t];
        int o = val;
        if (val == INT_MAX) o = -1;
        else if (t > 0 && val == s[t - 1]) o = -1;
        dpids[b * NPIDS + t] = o;
    }
}

// 3-way bf16 split: a ~= h + m + l, residual <= 2^-26 |a|.
// r1 = a - (float)h and r2 = r1 - (float)m are exact (Sterbenz).
__device__ __forceinline__ void split3(float a, __bf16& h, __bf16& m, __bf16& l) {
    h = (__bf16)a;
    float r1 = a - (float)h;
    m = (__bf16)r1;
    float r2 = r1 - (float)m;
    l = (__bf16)r2;
}

// ---------------- Kernel 2: MaxSim via split-bf16 MFMA ----------------
// One wave per 2 consecutive candidates (always same batch: 500 even, pairs
// even-aligned). Q[b] (32x128) lives in registers as 3x8 bf16x8 A-fragments
// for mfma_f32_32x32x16_bf16 (lane: q-row = lane&31, k-half = lane>>5).
// Per candidate: 7 token-tiles of 32 (clamped at 199); per tile 8 K-steps x
// 5 MFMAs (hh, hm, mh, hl, lh). acc C-layout: col(token)=lane&31,
// row(q)=f(reg,lane>>5) -> elementwise running max over tiles, cross-lane
// max (5 shfl) + double-sum at the end. All reductions are invariant to
// row/col permutations, and A/B use identical k-packing so any internal
// k-permutation cancels.
__global__ __launch_bounds__(256) void score_kernel(const float* __restrict__ qv,
                                                    const float* __restrict__ vectors,
                                                    const int* __restrict__ dpids,
                                                    float* __restrict__ scores) {
    const int t    = threadIdx.x;
    const int w    = t >> 6;
    const int lane = t & 63;
    const int row  = lane & 31;     // q-row for A, token-in-tile for B
    const int half = lane >> 5;     // k-half selector

    const int cbase = (blockIdx.x * 4 + w) * 2;
    const int b     = cbase / NPIDS;

    // ---- load + split Q fragments (stationary for both candidates) ----
    bf16x8 qh[8], qm[8], ql[8];
    {
        const float* qb = qv + ((size_t)b * QLEN + row) * HDIM + half * 8;
        #pragma unroll
        for (int ks = 0; ks < 8; ++ks) {
            const float4 a0 = *(const float4*)(qb + ks * 16);
            const float4 a1 = *(const float4*)(qb + ks * 16 + 4);
            float f[8] = {a0.x, a0.y, a0.z, a0.w, a1.x, a1.y, a1.z, a1.w};
            bf16x8 H, M, L;
            #pragma unroll
            for (int j = 0; j < 8; ++j) {
                __bf16 hh, mm, ll;
                split3(f[j], hh, mm, ll);
                H[j] = hh; M[j] = mm; L[j] = ll;
            }
            qh[ks] = H; qm[ks] = M; ql[ks] = L;
        }
    }

    for (int ci = 0; ci < 2; ++ci) {
        const int c   = cbase + ci;
        const int pid = dpids[c];
        if (pid < 0) {
            if (lane == 0) scores[c] = -__builtin_inff();
            continue;
        }

        const float* vb = vectors + (size_t)pid * VROW + half * 8;

        float rmax[16];
        #pragma unroll
        for (int j = 0; j < 16; ++j) rmax[j] = -FLT_MAX;

        for (int tile = 0; tile < 7; ++tile) {
            int tok = tile * 32 + row;
            if (tok > DLEN - 1) tok = DLEN - 1;          // dup token 199: max-safe
            const float* vt = vb + (size_t)tok * HDIM;

            f32x16 acc;
            #pragma unroll
            for (int j = 0; j < 16; ++j) acc[j] = 0.0f;

            #pragma unroll
            for (int ks = 0; ks < 8; ++ks) {
                const float4 c0 = *(const float4*)(vt + ks * 16);
                const float4 c1 = *(const float4*)(vt + ks * 16 + 4);
                float f[8] = {c0.x, c0.y, c0.z, c0.w, c1.x, c1.y, c1.z, c1.w};
                bf16x8 vh, vm, vl;
                #pragma unroll
                for (int j = 0; j < 8; ++j) {
                    __bf16 hh, mm, ll;
                    split3(f[j], hh, mm, ll);
                    vh[j] = hh; vm[j] = mm; vl[j] = ll;
                }
                acc = __builtin_amdgcn_mfma_f32_32x32x16_bf16(qh[ks], vh, acc, 0, 0, 0);
                acc = __builtin_amdgcn_mfma_f32_32x32x16_bf16(qh[ks], vm, acc, 0, 0, 0);
                acc = __builtin_amdgcn_mfma_f32_32x32x16_bf16(qm[ks], vh, acc, 0, 0, 0);
                acc = __builtin_amdgcn_mfma_f32_32x32x16_bf16(qh[ks], vl, acc, 0, 0, 0);
                acc = __builtin_amdgcn_mfma_f32_32x32x16_bf16(ql[ks], vh, acc, 0, 0, 0);
            }

            #pragma unroll
            for (int j = 0; j < 16; ++j) rmax[j] = fmaxf(rmax[j], acc[j]);
        }

        // cross-lane max over the 32 token-columns for each of this lane's
        // 16 q-rows, then sum all 32 q-row maxes in double.
        double dsum = 0.0;
        #pragma unroll
        for (int j = 0; j < 16; ++j) {
            float m = rmax[j];
            m = fmaxf(m, __shfl_xor(m, 1));
            m = fmaxf(m, __shfl_xor(m, 2));
            m = fmaxf(m, __shfl_xor(m, 4));
            m = fmaxf(m, __shfl_xor(m, 8));
            m = fmaxf(m, __shfl_xor(m, 16));
            dsum += (double)m;
        }
        dsum += __shfl_xor(dsum, 32);   // combine the two row-half sets
        if (lane == 0) scores[c] = (float)dsum;
    }
}

// ---------------- Kernel 3: per-batch top-100 (sorted desc) ----------------
__global__ __launch_bounds__(512) void topk_kernel(const float* __restrict__ scores,
                                                   const int* __restrict__ dpids,
                                                   const int* __restrict__ boundaries,
                                                   float* __restrict__ out) {
    __shared__ float ss[512];
    __shared__ int   sp[512];
    const int b = blockIdx.x;
    const int t = threadIdx.x;
    const int lo = boundaries[0];

    float sc = -__builtin_inff();
    int   p  = -1;
    if (t < NPIDS) {
        p = dpids[b * NPIDS + t];
        sc = (p < 0) ? -__builtin_inff() : scores[b * NPIDS + t];
    }
    ss[t] = sc;
    sp[t] = p;
    __syncthreads();

    for (int k = 2; k <= 512; k <<= 1) {
        for (int j = k >> 1; j > 0; j >>= 1) {
            int ixj = t ^ j;
            if (ixj > t) {
                float a = ss[t], c = ss[ixj];
                bool down = ((t & k) == 0);
                bool swap = down ? (a < c) : (a > c);
                if (swap) {
                    int pa = sp[t], pc = sp[ixj];
                    ss[t] = c;   ss[ixj] = a;
                    sp[t] = pc;  sp[ixj] = pa;
                }
            }
            __syncthreads();
        }
    }

    if (t < TOPK) {
        out[b * TOPK + t] = ss[t];
        int pp = sp[t];
        out[NB * TOPK + b * TOPK + t] = (pp >= 0) ? (float)(pp + lo) : -1.0f;
    }
}

// ---------------- launch ----------------
extern "C" void kernel_launch(void* const* d_in, const int* in_sizes, int n_in,
                              void* d_out, int out_size, void* d_ws, size_t ws_size,
                              hipStream_t stream) {
    const float* qv        = (const float*)d_in[0];
    const int*   pids      = (const int*)d_in[1];
    const float* vectors   = (const float*)d_in[2];
    const int*   boundaries= (const int*)d_in[3];

    int*   dpids  = (int*)d_ws;
    float* scores = (float*)((char*)d_ws + ((NB * NPIDS * sizeof(int) + 255) & ~255));

    dedupe_kernel<<<NB, 512, 0, stream>>>(pids, boundaries, dpids);
    score_kernel<<<(NB * NPIDS) / 8, 256, 0, stream>>>(qv, vectors, dpids, scores);
    topk_kernel<<<NB, 512, 0, stream>>>(scores, dpids, boundaries, (float*)d_out);
}